// Round 1
// baseline (272.436 us; speedup 1.0000x reference)
//
#include <hip/hip_runtime.h>

namespace {

constexpr int T  = 30;
constexpr int C  = 4;
constexpr int HW = 256 * 256;
constexpr int B  = 8;

__global__ __launch_bounds__(256) void interp_kernel(
    const float* __restrict__ images,
    const float* __restrict__ mask,
    const float* __restrict__ days,
    float* __restrict__ out)
{
    __shared__ float s_day[T];
    const int b = blockIdx.x >> 8;              // 256 blocks per batch image
    if (threadIdx.x < T) s_day[threadIdx.x] = days[b * T + threadIdx.x];
    __syncthreads();

    const int hw = ((blockIdx.x & 255) << 8) | threadIdx.x;

    const size_t pixBase = (size_t)b * T * C * HW + hw;
    const float* ibase = images + pixBase;
    float*       obase = out    + pixBase;
    const float* mbase = mask + (size_t)b * T * HW + hw;

    // 30-bit visibility mask (visible where cloud_mask == 0)
    unsigned vis = 0u;
#pragma unroll
    for (int t = 0; t < T; ++t)
        vis |= (mbase[(size_t)t * HW] == 0.0f ? 1u : 0u) << t;

    int   left = -1;
    float l0 = 0.f, l1 = 0.f, l2 = 0.f, l3 = 0.f, dl = 0.f;

    for (int t = 0; t < T; ++t) {
        if (vis & (1u << t)) {
            const float* p = ibase + (size_t)t * (C * HW);
            const float v0 = p[0];
            const float v1 = p[HW];
            const float v2 = p[2 * HW];
            const float v3 = p[3 * HW];

            // visible frame: out = image
            float* o = obase + (size_t)t * (C * HW);
            o[0]      = v0;
            o[HW]     = v1;
            o[2 * HW] = v2;
            o[3 * HW] = v3;

            const float dt = s_day[t];
            if (left < 0) {
                // leading span: only next visible exists -> img_next
                for (int u = 0; u < t; ++u) {
                    float* ou = obase + (size_t)u * (C * HW);
                    ou[0]      = v0;
                    ou[HW]     = v1;
                    ou[2 * HW] = v2;
                    ou[3 * HW] = v3;
                }
            } else {
                // interior span: linear interpolation in day-space
                float denom = dt - dl;
                denom = (denom == 0.0f) ? 1.0f : denom;
                const float inv = 1.0f / denom;
                for (int u = left + 1; u < t; ++u) {
                    const float f  = (s_day[u] - dl) * inv;
                    float* ou = obase + (size_t)u * (C * HW);
                    ou[0]      = fmaf(f, v0 - l0, l0);
                    ou[HW]     = fmaf(f, v1 - l1, l1);
                    ou[2 * HW] = fmaf(f, v2 - l2, l2);
                    ou[3 * HW] = fmaf(f, v3 - l3, l3);
                }
            }
            left = t;
            l0 = v0; l1 = v1; l2 = v2; l3 = v3;
            dl = dt;
        }
    }

    if (left < 0) {
        // never visible -> NaN everywhere
        const float nanv = __int_as_float(0x7fc00000);
        for (int u = 0; u < T; ++u) {
            float* ou = obase + (size_t)u * (C * HW);
            ou[0]      = nanv;
            ou[HW]     = nanv;
            ou[2 * HW] = nanv;
            ou[3 * HW] = nanv;
        }
    } else {
        // trailing span: only last visible exists -> img_last
        for (int u = left + 1; u < T; ++u) {
            float* ou = obase + (size_t)u * (C * HW);
            ou[0]      = l0;
            ou[HW]     = l1;
            ou[2 * HW] = l2;
            ou[3 * HW] = l3;
        }
    }
}

} // namespace

extern "C" void kernel_launch(void* const* d_in, const int* in_sizes, int n_in,
                              void* d_out, int out_size, void* d_ws, size_t ws_size,
                              hipStream_t stream)
{
    const float* images = (const float*)d_in[0];
    const float* mask   = (const float*)d_in[1];
    const float* days   = (const float*)d_in[2];
    float* out          = (float*)d_out;

    const int nPix = B * HW;                 // one thread per (b, h, w)
    dim3 grid(nPix / 256), block(256);
    hipLaunchKernelGGL(interp_kernel, grid, block, 0, stream,
                       images, mask, days, out);
}

// Round 2
// 250.385 us; speedup vs baseline: 1.0881x; 1.0881x over previous
//
#include <hip/hip_runtime.h>

namespace {

constexpr int T  = 30;
constexpr int C  = 4;
constexpr int HW = 256 * 256;
constexpr int B  = 8;

// One thread per (b,h,w) pixel. All interpolation writes go to an LDS
// column owned exclusively by this thread (bank = tid%32 for every row ->
// conflict-free, and no cross-thread sharing -> no __syncthreads in the
// channel loop). Global writes are then a dense coalesced flush: exactly
// one 4B store per output element.
__global__ __launch_bounds__(256) void interp_kernel(
    const float* __restrict__ images,
    const float* __restrict__ mask,
    const float* __restrict__ days,
    float* __restrict__ out)
{
    __shared__ float s_day[T];
    __shared__ float s_tile[T][256];   // 30 KB

    const int tid = threadIdx.x;
    const int b = blockIdx.x >> 8;              // 256 blocks per batch image
    if (tid < T) s_day[tid] = days[b * T + tid];
    __syncthreads();

    const int hw = ((blockIdx.x & 255) << 8) | tid;

    const float* mbase = mask + (size_t)b * T * HW + hw;

    // 30-bit visibility mask (visible where cloud_mask == 0)
    unsigned vis = 0u;
#pragma unroll
    for (int t = 0; t < T; ++t)
        vis |= (mbase[(size_t)t * HW] == 0.0f ? 1u : 0u) << t;

    const size_t pixBase = (size_t)b * T * C * HW + hw;

    for (int c = 0; c < C; ++c) {
        const float* ib = images + pixBase + (size_t)c * HW;

        int   left = -1;
        float lval = 0.f, dl = 0.f;

        for (int t = 0; t < T; ++t) {
            if (vis & (1u << t)) {
                const float v  = ib[(size_t)t * (C * HW)];
                const float dt = s_day[t];
                s_tile[t][tid] = v;                     // visible frame
                if (left < 0) {
                    // leading span: only next visible -> img_next
                    for (int u = 0; u < t; ++u)
                        s_tile[u][tid] = v;
                } else {
                    float denom = dt - dl;
                    denom = (denom == 0.0f) ? 1.0f : denom;
                    const float inv = 1.0f / denom;
                    for (int u = left + 1; u < t; ++u) {
                        const float f = (s_day[u] - dl) * inv;
                        s_tile[u][tid] = fmaf(f, v - lval, lval);
                    }
                }
                left = t;
                lval = v;
                dl   = dt;
            }
        }

        if (left < 0) {
            const float nanv = __int_as_float(0x7fc00000);
            for (int u = 0; u < T; ++u)
                s_tile[u][tid] = nanv;                  // never visible
        } else {
            for (int u = left + 1; u < T; ++u)
                s_tile[u][tid] = lval;                  // trailing span
        }

        // Dense coalesced flush: wave writes 256B-contiguous per t-plane.
        float* ob = out + pixBase + (size_t)c * HW;
#pragma unroll
        for (int t = 0; t < T; ++t)
            ob[(size_t)t * (C * HW)] = s_tile[t][tid];
    }
}

} // namespace

extern "C" void kernel_launch(void* const* d_in, const int* in_sizes, int n_in,
                              void* d_out, int out_size, void* d_ws, size_t ws_size,
                              hipStream_t stream)
{
    const float* images = (const float*)d_in[0];
    const float* mask   = (const float*)d_in[1];
    const float* days   = (const float*)d_in[2];
    float* out          = (float*)d_out;

    const int nPix = B * HW;                 // one thread per (b, h, w)
    dim3 grid(nPix / 256), block(256);
    hipLaunchKernelGGL(interp_kernel, grid, block, 0, stream,
                       images, mask, days, out);
}

// Round 3
// 177.780 us; speedup vs baseline: 1.5324x; 1.4084x over previous
//
#include <hip/hip_runtime.h>

namespace {

constexpr int T   = 30;
constexpr int C   = 4;
constexpr int HW  = 256 * 256;
constexpr int B   = 8;
constexpr int CHW = C * HW;

// One thread per (b,h,w). Fully predicated (no divergent control flow):
// value-carrying forward/backward scans in registers, compile-time-indexed
// register arrays only (no scratch), dense coalesced loads/stores.
__global__ __launch_bounds__(256, 4) void interp_kernel(
    const float* __restrict__ images,
    const float* __restrict__ mask,
    const float* __restrict__ days,
    float* __restrict__ out)
{
    __shared__ float s_day[T];
    const int tid = threadIdx.x;
    const int b   = blockIdx.x >> 8;            // 256 blocks per batch image
    if (tid < T) s_day[tid] = days[b * T + tid];
    __syncthreads();

    const int hw = ((blockIdx.x & 255) << 8) | tid;

    // ---- visibility bitmask: 30 dense loads, all in flight ----
    const float* mbase = mask + (size_t)b * T * HW + hw;
    float mv[T];
#pragma unroll
    for (int t = 0; t < T; ++t) mv[t] = mbase[(size_t)t * HW];
    unsigned vis = 0u;
#pragma unroll
    for (int t = 0; t < T; ++t) vis |= (mv[t] == 0.0f ? 1u : 0u) << t;

    // ---- per-pixel frac[t], computed once, reused for all channels ----
    // backward scan: day of next visible
    float dn[T];
    {
        float run = 0.0f;
#pragma unroll
        for (int t = T - 1; t >= 0; --t) {
            const bool v = (vis >> t) & 1u;
            run = v ? s_day[t] : run;
            dn[t] = run;
        }
    }
    float frac[T];
    {
        float dl = 0.0f;
#pragma unroll
        for (int t = 0; t < T; ++t) {
            const bool v = (vis >> t) & 1u;
            dl = v ? s_day[t] : dl;
            const bool lv_ok = (vis & ((1u << (t + 1)) - 1u)) != 0u;
            const bool nv_ok = (vis >> t) != 0u;
            float denom = dn[t] - dl;
            denom = (denom == 0.0f) ? 1.0f : denom;
            const float f = (s_day[t] - dl) / denom;
            // both -> f; only_next -> 1 (with vlast=0 gives exact img_next);
            // only_last / none -> 0
            frac[t] = (lv_ok && nv_ok) ? f : (nv_ok ? 1.0f : 0.0f);
        }
    }

    const bool  none = (vis == 0u);
    const float nanv = __int_as_float(0x7fc00000);
    const size_t pixBase = (size_t)b * T * CHW + hw;

    for (int c = 0; c < C; ++c) {
        const float* ib = images + pixBase + (size_t)c * HW;
        float*       ob = out    + pixBase + (size_t)c * HW;

        // dense loads: 30 independent vmem ops issued back-to-back
        float img[T];
#pragma unroll
        for (int t = 0; t < T; ++t) img[t] = ib[(size_t)t * CHW];

        // backward value-scan: next visible value
        float nv[T];
        {
            float run = 0.0f;
#pragma unroll
            for (int t = T - 1; t >= 0; --t) {
                const bool v = (vis >> t) & 1u;
                run = v ? img[t] : run;
                nv[t] = run;
            }
        }
        // forward value-scan + blend + dense store
        {
            float rl = 0.0f;   // last visible value (0 before first visible)
#pragma unroll
            for (int t = 0; t < T; ++t) {
                const bool v = (vis >> t) & 1u;
                rl = v ? img[t] : rl;
                const float res = fmaf(frac[t], nv[t] - rl, rl);
                ob[(size_t)t * CHW] = none ? nanv : res;
            }
        }
    }
}

} // namespace

extern "C" void kernel_launch(void* const* d_in, const int* in_sizes, int n_in,
                              void* d_out, int out_size, void* d_ws, size_t ws_size,
                              hipStream_t stream)
{
    const float* images = (const float*)d_in[0];
    const float* mask   = (const float*)d_in[1];
    const float* days   = (const float*)d_in[2];
    float* out          = (float*)d_out;

    const int nPix = B * HW;                 // one thread per (b, h, w)
    dim3 grid(nPix / 256), block(256);
    hipLaunchKernelGGL(interp_kernel, grid, block, 0, stream,
                       images, mask, days, out);
}

// Round 4
// 111.385 us; speedup vs baseline: 2.4459x; 1.5961x over previous
//
#include <hip/hip_runtime.h>

namespace {

constexpr int T   = 30;
constexpr int C   = 4;
constexpr int HW  = 256 * 256;
constexpr int B   = 8;
constexpr int CHW = C * HW;

// One thread per (b,h,w). Fully predicated scans in registers.
// Key register trick: at a visible t, nv[t] == img[t], so the forward
// "last visible value" scan can run off nv[] and img[] never needs to be
// live -> ~75 VGPR live set. waves_per_eu(4,4) pins the allocator at the
// 128-VGPR budget so it doesn't squeeze to 64 and spill (R3's failure).
__global__ __attribute__((amdgpu_flat_work_group_size(256, 256)))
           __attribute__((amdgpu_waves_per_eu(4, 4)))
void interp_kernel(
    const float* __restrict__ images,
    const float* __restrict__ mask,
    const float* __restrict__ days,
    float* __restrict__ out)
{
    __shared__ float s_day[T];
    const int tid = threadIdx.x;
    const int b   = blockIdx.x >> 8;            // 256 blocks per batch image
    if (tid < T) s_day[tid] = days[b * T + tid];
    __syncthreads();

    const int hw = ((blockIdx.x & 255) << 8) | tid;

    // ---- visibility bitmask: 30 dense streaming loads ----
    const float* mbase = mask + (size_t)b * T * HW + hw;
    unsigned vis = 0u;
#pragma unroll
    for (int t = 0; t < T; ++t) {
        const float m = __builtin_nontemporal_load(&mbase[(size_t)t * HW]);
        vis |= (m == 0.0f ? 1u : 0u) << t;
    }

    // ---- per-pixel frac[t], computed once, reused for all channels ----
    float frac[T];
    {
        float dn[T];                    // day of next visible (backward scan)
        float run = 0.0f;
#pragma unroll
        for (int t = T - 1; t >= 0; --t) {
            run = ((vis >> t) & 1u) ? s_day[t] : run;
            dn[t] = run;
        }
        float dl = 0.0f;                // day of last visible (forward scan)
#pragma unroll
        for (int t = 0; t < T; ++t) {
            const bool v = (vis >> t) & 1u;
            dl = v ? s_day[t] : dl;
            const bool lv_ok = (vis & ((1u << (t + 1)) - 1u)) != 0u;
            const bool nv_ok = (vis >> t) != 0u;
            float denom = dn[t] - dl;
            denom = (denom == 0.0f) ? 1.0f : denom;
            const float f = (s_day[t] - dl) / denom;
            // visible -> 0 (dl==day[t]); both -> f; only_next -> 1 (rl==0
            // gives exact img_next); only_last / none -> 0 (gives rl)
            frac[t] = (lv_ok && nv_ok) ? f : (nv_ok ? 1.0f : 0.0f);
        }
    }

    const bool  none = (vis == 0u);
    const float nanv = __int_as_float(0x7fc00000);
    const size_t pixBase = (size_t)b * T * CHW + hw;

    for (int c = 0; c < C; ++c) {
        const float* ib = images + pixBase + (size_t)c * HW;
        float*       ob = out    + pixBase + (size_t)c * HW;

        // backward value-scan fused with loads: nv[t] = next visible value
        float nv[T];
        {
            float run = 0.0f;
#pragma unroll
            for (int t = T - 1; t >= 0; --t) {
                const float v = __builtin_nontemporal_load(&ib[(size_t)t * CHW]);
                run = ((vis >> t) & 1u) ? v : run;
                nv[t] = run;
            }
        }
        // forward value-scan off nv[] (rl = nv[t] at visible t) + store
        {
            float rl = 0.0f;
#pragma unroll
            for (int t = 0; t < T; ++t) {
                rl = ((vis >> t) & 1u) ? nv[t] : rl;
                const float res = fmaf(frac[t], nv[t] - rl, rl);
                __builtin_nontemporal_store(none ? nanv : res,
                                            &ob[(size_t)t * CHW]);
            }
        }
    }
}

} // namespace

extern "C" void kernel_launch(void* const* d_in, const int* in_sizes, int n_in,
                              void* d_out, int out_size, void* d_ws, size_t ws_size,
                              hipStream_t stream)
{
    const float* images = (const float*)d_in[0];
    const float* mask   = (const float*)d_in[1];
    const float* days   = (const float*)d_in[2];
    float* out          = (float*)d_out;

    const int nPix = B * HW;                 // one thread per (b, h, w)
    dim3 grid(nPix / 256), block(256);
    hipLaunchKernelGGL(interp_kernel, grid, block, 0, stream,
                       images, mask, days, out);
}